// Round 1
// baseline (163.455 us; speedup 1.0000x reference)
//
#include <hip/hip_runtime.h>
#include <math.h>

// Problem constants
constexpr int B_ = 8;
constexpr int N_ = 400;
constexpr int D_ = 768;
constexpr int M_ = 160;                 // int(0.4 * 400)
constexpr int PAIRS_ = M_ * (M_ - 1);   // 25440

// Workspace layout (bytes):
//   z      : double[B_*N_]   @ 0       (25600 B)
//   pos    : int[B_*M_]      @ 25600   (5120 B)
//   aterm  : float[B_*M_*3]  @ 30720   (15360 B)  (includes b_pair)
//   bterm  : float[B_*M_*3]  @ 46080   (15360 B)

// ---------------------------------------------------------------------------
// Kernel 1: z[b,n] = dot(x[b,n,:], w_span)  (fp64 accumulation; sigmoid is
// monotonic so ranking on z == ranking on h)
// One wave per row; 3200 rows -> 800 blocks of 256.
__global__ __launch_bounds__(256) void k_span(const float* __restrict__ x,
                                              const float* __restrict__ w_span,
                                              double* __restrict__ z) {
  int wg = blockIdx.x * 4 + (threadIdx.x >> 6);
  int lane = threadIdx.x & 63;
  const float* xr = x + (size_t)wg * D_;
  double acc = 0.0;
#pragma unroll
  for (int k = 0; k < D_ / 64; ++k) {
    int d = lane + (k << 6);
    acc += (double)xr[d] * (double)w_span[d];
  }
#pragma unroll
  for (int off = 32; off > 0; off >>= 1)
    acc += __shfl_down(acc, off, 64);
  if (lane == 0) z[wg] = acc;
}

// ---------------------------------------------------------------------------
// Kernel 2: per batch, rank[i] (i<M) = stable descending rank of z[i];
// pos = sorted ascending of those ranks. One block per batch.
__global__ __launch_bounds__(256) void k_rank(const double* __restrict__ z,
                                              int* __restrict__ pos) {
  __shared__ double zsh[N_];
  __shared__ int ranksh[M_];
  int b = blockIdx.x;
  int t = threadIdx.x;
  for (int j = t; j < N_; j += 256) zsh[j] = z[b * N_ + j];
  __syncthreads();
  if (t < M_) {
    double zi = zsh[t];
    int cnt = 0;
    for (int j = 0; j < N_; ++j) {
      double zj = zsh[j];
      cnt += (zj > zi) || (zj == zi && j < t);
    }
    ranksh[t] = cnt;
  }
  __syncthreads();
  if (t < M_) {
    int r = ranksh[t];
    int slot = 0;
#pragma unroll 8
    for (int k = 0; k < M_; ++k) slot += (ranksh[k] < r);
    pos[b * M_ + slot] = r;  // sorted ascending since ranks are distinct
  }
}

// ---------------------------------------------------------------------------
// Kernel 3: aterm[b,i,c] = dot(x_r, w1[:,c]) + b_pair[c];
//           bterm[b,i,c] = dot(x_r, w2[:,c]).  One wave per (b,i).
__global__ __launch_bounds__(256) void k_ab(const float* __restrict__ x,
                                            const float* __restrict__ w_pair,
                                            const float* __restrict__ b_pair,
                                            const int* __restrict__ pos,
                                            float* __restrict__ aterm,
                                            float* __restrict__ bterm) {
  int wg = blockIdx.x * 4 + (threadIdx.x >> 6);  // = b*M_ + i
  int lane = threadIdx.x & 63;
  int b = wg / M_;
  int row = pos[wg];
  const float* xr = x + ((size_t)(b * N_ + row)) * D_;
  float a0 = 0, a1 = 0, a2 = 0, c0 = 0, c1 = 0, c2 = 0;
#pragma unroll 4
  for (int k = 0; k < D_ / 64; ++k) {
    int d = lane + (k << 6);
    float xv = xr[d];
    a0 += xv * w_pair[d * 3 + 0];
    a1 += xv * w_pair[d * 3 + 1];
    a2 += xv * w_pair[d * 3 + 2];
    c0 += xv * w_pair[(D_ + d) * 3 + 0];
    c1 += xv * w_pair[(D_ + d) * 3 + 1];
    c2 += xv * w_pair[(D_ + d) * 3 + 2];
  }
#pragma unroll
  for (int off = 32; off > 0; off >>= 1) {
    a0 += __shfl_down(a0, off, 64);
    a1 += __shfl_down(a1, off, 64);
    a2 += __shfl_down(a2, off, 64);
    c0 += __shfl_down(c0, off, 64);
    c1 += __shfl_down(c1, off, 64);
    c2 += __shfl_down(c2, off, 64);
  }
  if (lane == 0) {
    aterm[wg * 3 + 0] = a0 + b_pair[0];
    aterm[wg * 3 + 1] = a1 + b_pair[1];
    aterm[wg * 3 + 2] = a2 + b_pair[2];
    bterm[wg * 3 + 0] = c0;
    bterm[wg * 3 + 1] = c1;
    bterm[wg * 3 + 2] = c2;
  }
}

// ---------------------------------------------------------------------------
// Kernel 4: one block per (b, i). Stage y_c = x_i .* w3[:,c] in LDS, then
// each wave streams x_j rows and computes 3 dots per pair; epilogue =
// sigmoid -> softmax over C=3, write pair_probs.
__global__ __launch_bounds__(256) void k_pairs(const float* __restrict__ x,
                                               const float* __restrict__ w_pair,
                                               const int* __restrict__ pos,
                                               const float* __restrict__ aterm,
                                               const float* __restrict__ bterm,
                                               float* __restrict__ out_probs) {
  __shared__ float4 y0[D_ / 4], y1[D_ / 4], y2[D_ / 4];
  __shared__ float bsh[M_ * 3];
  __shared__ int possh[M_];
  __shared__ float ash[3];

  int b = blockIdx.x / M_;
  int i = blockIdx.x % M_;
  int t = threadIdx.x;

  if (t < M_) possh[t] = pos[b * M_ + t];
  for (int k = t; k < M_ * 3; k += 256) bsh[k] = bterm[b * M_ * 3 + k];
  if (t < 3) ash[t] = aterm[(b * M_ + i) * 3 + t];

  int row_i = pos[b * M_ + i];  // direct global read: avoids extra barrier
  const float* xi = x + ((size_t)(b * N_ + row_i)) * D_;
  const float* w3 = w_pair + 2 * D_ * 3;
  const float4* xi4 = (const float4*)xi;
  for (int q = t; q < D_ / 4; q += 256) {
    float4 xv = xi4[q];
    int d = q * 4;
    y0[q] = make_float4(xv.x * w3[(d + 0) * 3 + 0], xv.y * w3[(d + 1) * 3 + 0],
                        xv.z * w3[(d + 2) * 3 + 0], xv.w * w3[(d + 3) * 3 + 0]);
    y1[q] = make_float4(xv.x * w3[(d + 0) * 3 + 1], xv.y * w3[(d + 1) * 3 + 1],
                        xv.z * w3[(d + 2) * 3 + 1], xv.w * w3[(d + 3) * 3 + 1]);
    y2[q] = make_float4(xv.x * w3[(d + 0) * 3 + 2], xv.y * w3[(d + 1) * 3 + 2],
                        xv.z * w3[(d + 2) * 3 + 2], xv.w * w3[(d + 3) * 3 + 2]);
  }
  __syncthreads();

  int wave = t >> 6, lane = t & 63;
  for (int j = wave; j < M_; j += 4) {
    const float4* xj4 = (const float4*)(x + ((size_t)(b * N_ + possh[j])) * D_);
    float a0 = 0, a1 = 0, a2 = 0;
#pragma unroll
    for (int k = 0; k < 3; ++k) {
      int q = k * 64 + lane;
      float4 xv = xj4[q];
      float4 v0 = y0[q], v1 = y1[q], v2 = y2[q];
      a0 += xv.x * v0.x + xv.y * v0.y + xv.z * v0.z + xv.w * v0.w;
      a1 += xv.x * v1.x + xv.y * v1.y + xv.z * v1.z + xv.w * v1.w;
      a2 += xv.x * v2.x + xv.y * v2.y + xv.z * v2.z + xv.w * v2.w;
    }
#pragma unroll
    for (int off = 32; off > 0; off >>= 1) {
      a0 += __shfl_down(a0, off, 64);
      a1 += __shfl_down(a1, off, 64);
      a2 += __shfl_down(a2, off, 64);
    }
    if (lane == 0 && j != i) {
      float l0 = a0 + ash[0] + bsh[j * 3 + 0];
      float l1 = a1 + ash[1] + bsh[j * 3 + 1];
      float l2 = a2 + ash[2] + bsh[j * 3 + 2];
      float s0 = 1.0f / (1.0f + expf(-l0));
      float s1 = 1.0f / (1.0f + expf(-l1));
      float s2 = 1.0f / (1.0f + expf(-l2));
      float e0 = expf(s0), e1 = expf(s1), e2 = expf(s2);
      float inv = 1.0f / (e0 + e1 + e2);
      int jj = (j < i) ? j : (j - 1);
      size_t p = (size_t)b * PAIRS_ + (size_t)i * (M_ - 1) + jj;
      out_probs[p * 3 + 0] = e0 * inv;
      out_probs[p * 3 + 1] = e1 * inv;
      out_probs[p * 3 + 2] = e2 * inv;
    }
  }
}

// ---------------------------------------------------------------------------
// Kernel 5: pair_ranges as float4 per (b, pair): [ri0, ri1, rj0, rj1].
__global__ __launch_bounds__(256) void k_ranges(const int* __restrict__ span_ranges,
                                                const int* __restrict__ pos,
                                                float4* __restrict__ out_ranges) {
  int t = blockIdx.x * 256 + threadIdx.x;
  if (t >= B_ * PAIRS_) return;
  int b = t / PAIRS_;
  int p = t - b * PAIRS_;
  int i = p / (M_ - 1);
  int r = p - i * (M_ - 1);
  int j = r + (r >= i ? 1 : 0);
  int pi = pos[b * M_ + i];
  int pj = pos[b * M_ + j];
  float4 v;
  v.x = (float)span_ranges[pi * 2 + 0];
  v.y = (float)span_ranges[pi * 2 + 1];
  v.z = (float)span_ranges[pj * 2 + 0];
  v.w = (float)span_ranges[pj * 2 + 1];
  out_ranges[t] = v;
}

// ---------------------------------------------------------------------------
extern "C" void kernel_launch(void* const* d_in, const int* in_sizes, int n_in,
                              void* d_out, int out_size, void* d_ws, size_t ws_size,
                              hipStream_t stream) {
  const float* x = (const float*)d_in[0];
  const float* w_span = (const float*)d_in[1];
  // d_in[2] = b_span: constant shift, irrelevant to the ranking -> unused.
  const float* w_pair = (const float*)d_in[3];
  const float* b_pair = (const float*)d_in[4];
  const int* span_ranges = (const int*)d_in[5];

  char* ws = (char*)d_ws;
  double* z = (double*)ws;
  int* pos = (int*)(ws + 25600);
  float* aterm = (float*)(ws + 30720);
  float* bterm = (float*)(ws + 46080);

  float* out = (float*)d_out;
  float* out_probs = out;                                    // B*P*3 floats
  float4* out_ranges = (float4*)(out + (size_t)B_ * PAIRS_ * 3);  // B*P*4 floats

  k_span<<<(B_ * N_) / 4, 256, 0, stream>>>(x, w_span, z);
  k_rank<<<B_, 256, 0, stream>>>(z, pos);
  k_ab<<<(B_ * M_) / 4, 256, 0, stream>>>(x, w_pair, b_pair, pos, aterm, bterm);
  k_pairs<<<B_ * M_, 256, 0, stream>>>(x, w_pair, pos, aterm, bterm, out_probs);
  k_ranges<<<(B_ * PAIRS_ + 255) / 256, 256, 0, stream>>>(span_ranges, pos, out_ranges);
}

// Round 2
// 109.205 us; speedup vs baseline: 1.4968x; 1.4968x over previous
//
#include <hip/hip_runtime.h>
#include <math.h>

// Problem constants
constexpr int B_ = 8;
constexpr int N_ = 400;
constexpr int D_ = 768;
constexpr int M_ = 160;                 // int(0.4 * 400)
constexpr int PAIRS_ = M_ * (M_ - 1);   // 25440

typedef __attribute__((ext_vector_type(8))) short short8;   // 8 bf16 (4 VGPRs)
typedef __attribute__((ext_vector_type(4))) float floatx4;  // MFMA C/D

// Workspace layout (bytes):
//   z      : double[B_*N_]   @ 0       (25600 B)
//   pos    : int[B_*M_]      @ 25600   (5120 B)
//   aterm  : float[B_*M_*3]  @ 30720   (15360 B)  (includes b_pair)
//   bterm  : float[B_*M_*3]  @ 46080   (15360 B)

// ---------------------------------------------------------------------------
// Kernel 1: z[b,n] = dot(x[b,n,:], w_span)  (fp64 accumulation; sigmoid is
// monotonic so ranking on z == ranking on h). One wave per row.
__global__ __launch_bounds__(256) void k_span(const float* __restrict__ x,
                                              const float* __restrict__ w_span,
                                              double* __restrict__ z) {
  int wg = blockIdx.x * 4 + (threadIdx.x >> 6);
  int lane = threadIdx.x & 63;
  const float* xr = x + (size_t)wg * D_;
  double acc = 0.0;
#pragma unroll
  for (int k = 0; k < D_ / 64; ++k) {
    int d = lane + (k << 6);
    acc += (double)xr[d] * (double)w_span[d];
  }
#pragma unroll
  for (int off = 32; off > 0; off >>= 1)
    acc += __shfl_down(acc, off, 64);
  if (lane == 0) z[wg] = acc;
}

// ---------------------------------------------------------------------------
// Kernel 2: per batch, rank[i] (i<M) = stable descending rank of z[i];
// pos = sorted ascending of those ranks. One block per batch.
__global__ __launch_bounds__(256) void k_rank(const double* __restrict__ z,
                                              int* __restrict__ pos) {
  __shared__ double zsh[N_];
  __shared__ int ranksh[M_];
  int b = blockIdx.x;
  int t = threadIdx.x;
  for (int j = t; j < N_; j += 256) zsh[j] = z[b * N_ + j];
  __syncthreads();
  if (t < M_) {
    double zi = zsh[t];
    int cnt = 0;
    for (int j = 0; j < N_; ++j) {
      double zj = zsh[j];
      cnt += (zj > zi) || (zj == zi && j < t);
    }
    ranksh[t] = cnt;
  }
  __syncthreads();
  if (t < M_) {
    int r = ranksh[t];
    int slot = 0;
#pragma unroll 8
    for (int k = 0; k < M_; ++k) slot += (ranksh[k] < r);
    pos[b * M_ + slot] = r;  // sorted ascending since ranks are distinct
  }
}

// ---------------------------------------------------------------------------
// Kernel 3: aterm[b,i,c] = dot(x_r, w1[:,c]) + b_pair[c];
//           bterm[b,i,c] = dot(x_r, w2[:,c]).  One wave per (b,i).
__global__ __launch_bounds__(256) void k_ab(const float* __restrict__ x,
                                            const float* __restrict__ w_pair,
                                            const float* __restrict__ b_pair,
                                            const int* __restrict__ pos,
                                            float* __restrict__ aterm,
                                            float* __restrict__ bterm) {
  int wg = blockIdx.x * 4 + (threadIdx.x >> 6);  // = b*M_ + i
  int lane = threadIdx.x & 63;
  int b = wg / M_;
  int row = pos[wg];
  const float* xr = x + ((size_t)(b * N_ + row)) * D_;
  float a0 = 0, a1 = 0, a2 = 0, c0 = 0, c1 = 0, c2 = 0;
#pragma unroll 4
  for (int k = 0; k < D_ / 64; ++k) {
    int d = lane + (k << 6);
    float xv = xr[d];
    a0 += xv * w_pair[d * 3 + 0];
    a1 += xv * w_pair[d * 3 + 1];
    a2 += xv * w_pair[d * 3 + 2];
    c0 += xv * w_pair[(D_ + d) * 3 + 0];
    c1 += xv * w_pair[(D_ + d) * 3 + 1];
    c2 += xv * w_pair[(D_ + d) * 3 + 2];
  }
#pragma unroll
  for (int off = 32; off > 0; off >>= 1) {
    a0 += __shfl_down(a0, off, 64);
    a1 += __shfl_down(a1, off, 64);
    a2 += __shfl_down(a2, off, 64);
    c0 += __shfl_down(c0, off, 64);
    c1 += __shfl_down(c1, off, 64);
    c2 += __shfl_down(c2, off, 64);
  }
  if (lane == 0) {
    aterm[wg * 3 + 0] = a0 + b_pair[0];
    aterm[wg * 3 + 1] = a1 + b_pair[1];
    aterm[wg * 3 + 2] = a2 + b_pair[2];
    bterm[wg * 3 + 0] = c0;
    bterm[wg * 3 + 1] = c1;
    bterm[wg * 3 + 2] = c2;
  }
}

// ---------------------------------------------------------------------------
// Split an fp32 value into bf16 hi (truncated) + bf16 lo (truncated residual).
// x ~= hi + lo with relative representation error < 2^-14.
__device__ inline void split8(const float* v, short8* hi, short8* lo) {
  short8 h, l;
#pragma unroll
  for (int e = 0; e < 8; ++e) {
    float f = v[e];
    unsigned int hb = __float_as_uint(f) & 0xffff0000u;
    h[e] = (short)(hb >> 16);
    float rest = f - __uint_as_float(hb);  // exact in fp32
    l[e] = (short)(__float_as_uint(rest) >> 16);
  }
  *hi = h;
  *lo = l;
}

// ---------------------------------------------------------------------------
// Kernel 4 (MFMA): one wave per (b, 16x16 output tile). For each channel c,
// S_c = (X_r .* w3_c) X_r^T via mfma_f32_16x16x32_bf16 with 3-term bf16
// split precision:  AhiBhi + AhiBlo + AloBhi.  Fragments loaded straight
// from global fp32 (L2-resident), converted in-register; no LDS.
// Epilogue: + aterm + bterm, sigmoid -> softmax, write probs AND ranges.
__global__ __launch_bounds__(256) void k_pairs(const float* __restrict__ x,
                                               const float* __restrict__ w_pair,
                                               const int* __restrict__ pos,
                                               const float* __restrict__ aterm,
                                               const float* __restrict__ bterm,
                                               const int* __restrict__ span_ranges,
                                               float* __restrict__ out_probs,
                                               float4* __restrict__ out_ranges) {
  int lane = threadIdx.x & 63;
  int w = blockIdx.x * 4 + (threadIdx.x >> 6);  // 0..799
  int b = w / 100;
  int t = w - b * 100;
  int ti = t / 10;            // i-tile (rows of output)
  int tj = t - ti * 10;       // j-tile (cols of output)
  int quad = lane >> 4;
  int l16 = lane & 15;

  // A operand: rows i = ti*16 + l16 of Y_c = X_r .* w3_c, k = quad*8+e
  // B operand: rows j = tj*16 + l16 of X_r (B[k][n] with n=l16), same k map.
  int i_lane = ti * 16 + l16;
  int j_lane = tj * 16 + l16;
  int pa = pos[b * M_ + i_lane];
  int pb = pos[b * M_ + j_lane];
  const float* xa = x + ((size_t)(b * N_ + pa)) * D_ + quad * 8;
  const float* xb = x + ((size_t)(b * N_ + pb)) * D_ + quad * 8;
  const float* w3 = w_pair + 2 * D_ * 3;

  floatx4 acc0 = {0.f, 0.f, 0.f, 0.f};
  floatx4 acc1 = {0.f, 0.f, 0.f, 0.f};
  floatx4 acc2 = {0.f, 0.f, 0.f, 0.f};

  for (int k = 0; k < D_; k += 32) {
    float xaf[8], xbf[8], wv[24];
    *(float4*)(xaf + 0) = *(const float4*)(xa + k + 0);
    *(float4*)(xaf + 4) = *(const float4*)(xa + k + 4);
    *(float4*)(xbf + 0) = *(const float4*)(xb + k + 0);
    *(float4*)(xbf + 4) = *(const float4*)(xb + k + 4);
    // w3 rows d0..d0+7, all 3 channels: 24 consecutive floats
    int d0 = k + quad * 8;
    const float* wp = w3 + (size_t)d0 * 3;
#pragma unroll
    for (int q = 0; q < 6; ++q) *(float4*)(wv + 4 * q) = *(const float4*)(wp + 4 * q);

    short8 bhi, blo;
    split8(xbf, &bhi, &blo);

#pragma unroll
    for (int c = 0; c < 3; ++c) {
      float y[8];
#pragma unroll
      for (int e = 0; e < 8; ++e) y[e] = xaf[e] * wv[e * 3 + c];
      short8 ahi, alo;
      split8(y, &ahi, &alo);
      floatx4 acc = (c == 0) ? acc0 : (c == 1) ? acc1 : acc2;
      acc = __builtin_amdgcn_mfma_f32_16x16x32_bf16(ahi, bhi, acc, 0, 0, 0);
      acc = __builtin_amdgcn_mfma_f32_16x16x32_bf16(ahi, blo, acc, 0, 0, 0);
      acc = __builtin_amdgcn_mfma_f32_16x16x32_bf16(alo, bhi, acc, 0, 0, 0);
      if (c == 0) acc0 = acc; else if (c == 1) acc1 = acc; else acc2 = acc;
    }
  }

  // Epilogue. C/D layout: col = lane&15 (j), row = quad*4 + reg (i).
  const float* at = aterm + (size_t)b * M_ * 3;
  const float* bt = bterm + (size_t)b * M_ * 3;
  int j = j_lane;
  float bj0 = bt[j * 3 + 0], bj1 = bt[j * 3 + 1], bj2 = bt[j * 3 + 2];
  int rj0 = span_ranges[pb * 2 + 0], rj1 = span_ranges[pb * 2 + 1];

#pragma unroll
  for (int r = 0; r < 4; ++r) {
    int i = ti * 16 + quad * 4 + r;
    if (i == j) continue;
    float l0 = acc0[r] + at[i * 3 + 0] + bj0;
    float l1 = acc1[r] + at[i * 3 + 1] + bj1;
    float l2 = acc2[r] + at[i * 3 + 2] + bj2;
    float s0 = 1.0f / (1.0f + expf(-l0));
    float s1 = 1.0f / (1.0f + expf(-l1));
    float s2 = 1.0f / (1.0f + expf(-l2));
    float e0 = expf(s0), e1 = expf(s1), e2 = expf(s2);
    float inv = 1.0f / (e0 + e1 + e2);
    int jj = j - (j > i ? 1 : 0);
    size_t p = (size_t)b * PAIRS_ + (size_t)i * (M_ - 1) + jj;
    out_probs[p * 3 + 0] = e0 * inv;
    out_probs[p * 3 + 1] = e1 * inv;
    out_probs[p * 3 + 2] = e2 * inv;
    int pi = pos[b * M_ + i];
    float4 rg;
    rg.x = (float)span_ranges[pi * 2 + 0];
    rg.y = (float)span_ranges[pi * 2 + 1];
    rg.z = (float)rj0;
    rg.w = (float)rj1;
    out_ranges[p] = rg;
  }
}

// ---------------------------------------------------------------------------
extern "C" void kernel_launch(void* const* d_in, const int* in_sizes, int n_in,
                              void* d_out, int out_size, void* d_ws, size_t ws_size,
                              hipStream_t stream) {
  const float* x = (const float*)d_in[0];
  const float* w_span = (const float*)d_in[1];
  // d_in[2] = b_span: constant shift, irrelevant to the ranking -> unused.
  const float* w_pair = (const float*)d_in[3];
  const float* b_pair = (const float*)d_in[4];
  const int* span_ranges = (const int*)d_in[5];

  char* ws = (char*)d_ws;
  double* z = (double*)ws;
  int* pos = (int*)(ws + 25600);
  float* aterm = (float*)(ws + 30720);
  float* bterm = (float*)(ws + 46080);

  float* out = (float*)d_out;
  float* out_probs = out;                                         // B*P*3 floats
  float4* out_ranges = (float4*)(out + (size_t)B_ * PAIRS_ * 3);  // B*P*4 floats

  k_span<<<(B_ * N_) / 4, 256, 0, stream>>>(x, w_span, z);
  k_rank<<<B_, 256, 0, stream>>>(z, pos);
  k_ab<<<(B_ * M_) / 4, 256, 0, stream>>>(x, w_pair, b_pair, pos, aterm, bterm);
  k_pairs<<<(B_ * 100) / 4, 256, 0, stream>>>(x, w_pair, pos, aterm, bterm,
                                              span_ranges, out_probs, out_ranges);
}